// Round 1
// baseline (1059.619 us; speedup 1.0000x reference)
//
#include <hip/hip_runtime.h>
#include <math.h>

constexpr int kN = 20000;
constexpr int kD = 8;
constexpr int kE = 100000;
constexpr int kM = kN * 9;            // 180000 level-1 rows
constexpr int kTiles1 = kM / 8;       // 22500
constexpr int kTiles3 = kN / 4;       // 5000
constexpr float kEps = 1e-5f;

// stats/params layout (float indices) inside ws stats block
constexpr int S_SUM1 = 0, S_SQ1 = 128, S_SUM2 = 256, S_SQ2 = 320;
constexpr int P_SC1 = 384, P_SH1 = 512, P_SC2 = 640, P_SH2 = 704;

// ws byte offsets
constexpr size_t OFF_PRE2  = 46080000;   // after pre1 bf16 [kM][128]
constexpr size_t OFF_EMBS  = 51200000;
constexpr size_t OFF_EMBSW = 56320000;
constexpr size_t OFF_STATS = 61440000;

__device__ __forceinline__ float rl(float v, int l) {
  return __uint_as_float(__builtin_amdgcn_readlane(__float_as_uint(v), l));
}
__device__ __forceinline__ unsigned f2bf(float f) {  // f32 -> bf16 (RNE)
  unsigned u = __float_as_uint(f);
  u += 0x7fffu + ((u >> 16) & 1u);
  return u >> 16;
}

// K1: level-1 masked-mean gather + GEMM1 (agg1 @ W1 + b1) + BN1 stats.
// One wave per 8-row tile; lane = feature for the gather, lane = col-pair
// (2l, 2l+1) for the GEMM. agg broadcast via v_readlane (VALU pipe, NOT
// __shfl which lowers to ds_bpermute on the LDS pipe); W1 from LDS as
// float4 k-pairs -> 32 ds_read_b128 per 8 rows.
__global__ __launch_bounds__(256) void k1_agg_gemm1(
    const float* __restrict__ x, const float* __restrict__ node_ts,
    const int* __restrict__ nidx, const float* __restrict__ nts,
    const float* __restrict__ W1, const float* __restrict__ b1,
    unsigned* __restrict__ pre1,   // packed bf16x2, [kM][64] dwords
    float* __restrict__ stats)
{
  __shared__ float4 W1s[32 * 64];
  __shared__ float4 red[4][64];
  const int tid = threadIdx.x;
  const int lane = tid & 63;
  const int wave = tid >> 6;

  const float2* W1f2 = (const float2*)W1;
  for (int i = tid; i < 2048; i += 256) {
    int kp = i >> 6, l = i & 63;
    float2 a = W1f2[(2 * kp) * 64 + l];
    float2 c = W1f2[(2 * kp + 1) * 64 + l];
    W1s[i] = make_float4(a.x, a.y, c.x, c.y);
  }
  __syncthreads();

  const float2 b1v = ((const float2*)b1)[lane];
  float ssum0 = 0.f, ssum1 = 0.f, ssq0 = 0.f, ssq1 = 0.f;
  const int gw = blockIdx.x * 4 + wave;
  const int nw = gridDim.x * 4;

  for (int tile = gw; tile < kTiles1; tile += nw) {
    const int m0 = tile * 8;
    float aggr[8];
#pragma unroll
    for (int r = 0; r < 8; ++r) {
      int m = m0 + r;
      int n = (int)((unsigned)m / 9u);
      int slot = m - n * 9;
      int c; float t;
      if (slot < kD) { c = nidx[n * kD + slot]; t = nts[n * kD + slot]; }
      else           { c = n;                   t = node_ts[n]; }
      float s = x[c * 64 + lane];
      int cnt = 1;
#pragma unroll
      for (int j = 0; j < kD; ++j) {
        float tj = nts[c * kD + j];
        if (tj <= t) { s += x[nidx[c * kD + j] * 64 + lane]; cnt++; }
      }
      aggr[r] = s / (float)cnt;
    }
    float acc0[8], acc1[8];
#pragma unroll
    for (int r = 0; r < 8; ++r) { acc0[r] = b1v.x; acc1[r] = b1v.y; }
#pragma unroll
    for (int kp = 0; kp < 32; ++kp) {
      float4 w = W1s[kp * 64 + lane];
#pragma unroll
      for (int r = 0; r < 8; ++r) {
        float a0 = rl(aggr[r], 2 * kp);
        float a1 = rl(aggr[r], 2 * kp + 1);
        acc0[r] += a0 * w.x + a1 * w.z;
        acc1[r] += a0 * w.y + a1 * w.w;
      }
    }
#pragma unroll
    for (int r = 0; r < 8; ++r) {
      float v0 = acc0[r], v1 = acc1[r];
      pre1[(m0 + r) * 64 + lane] = f2bf(v0) | (f2bf(v1) << 16);
      ssum0 += v0; ssq0 += v0 * v0; ssum1 += v1; ssq1 += v1 * v1;
    }
  }
  red[wave][lane] = make_float4(ssum0, ssum1, ssq0, ssq1);
  __syncthreads();
  if (wave == 0) {
    float4 a = red[0][lane], b = red[1][lane], c = red[2][lane], d = red[3][lane];
    atomicAdd(&stats[S_SUM1 + 2 * lane],     a.x + b.x + c.x + d.x);
    atomicAdd(&stats[S_SUM1 + 2 * lane + 1], a.y + b.y + c.y + d.y);
    atomicAdd(&stats[S_SQ1 + 2 * lane],      a.z + b.z + c.z + d.z);
    atomicAdd(&stats[S_SQ1 + 2 * lane + 1],  a.w + b.w + c.w + d.w);
  }
}

__global__ void k2_fin1(float* stats, const float* __restrict__ g1,
                        const float* __restrict__ be1) {
  int c = threadIdx.x;  // 128 threads
  float mean = stats[S_SUM1 + c] * (1.f / kM);
  float var  = stats[S_SQ1 + c] * (1.f / kM) - mean * mean;
  float sc   = g1[c] * rsqrtf(var + kEps);
  stats[P_SC1 + c] = sc;
  stats[P_SH1 + c] = be1[c] - mean * sc;
}

// K3: BN1+ReLU on pre1, masked mean over 9 child slots, GEMM2 + BN2 stats.
// One wave per 4-node tile; lane = feature-pair (2l,2l+1) for agg2,
// lane = output col o for GEMM2 (W2 as float4 k-quads in LDS).
__global__ __launch_bounds__(256) void k3_agg_gemm2(
    const unsigned* __restrict__ pre1, const float* __restrict__ node_ts,
    const float* __restrict__ nts,
    const float* __restrict__ W2, const float* __restrict__ b2,
    float* __restrict__ stats, float* __restrict__ pre2)
{
  __shared__ float4 W2s[32 * 64];
  __shared__ float2 red[4][64];
  const int tid = threadIdx.x;
  const int lane = tid & 63;
  const int wave = tid >> 6;
  for (int i = tid; i < 2048; i += 256) {
    int kq = i >> 6, o = i & 63;
    W2s[i] = make_float4(W2[(4 * kq + 0) * 64 + o], W2[(4 * kq + 1) * 64 + o],
                         W2[(4 * kq + 2) * 64 + o], W2[(4 * kq + 3) * 64 + o]);
  }
  __syncthreads();
  const float2 sc = make_float2(stats[P_SC1 + 2 * lane], stats[P_SC1 + 2 * lane + 1]);
  const float2 sh = make_float2(stats[P_SH1 + 2 * lane], stats[P_SH1 + 2 * lane + 1]);
  const float b2v = b2[lane];
  float ssum = 0.f, ssq = 0.f;
  const int gw = blockIdx.x * 4 + wave, nw = gridDim.x * 4;

  for (int tile = gw; tile < kTiles3; tile += nw) {
    const int n0 = tile * 4;
    float2 ag[4];
#pragma unroll
    for (int q = 0; q < 4; ++q) {
      int n = n0 + q;
      float tn = node_ts[n];
      float s0 = 0.f, s1 = 0.f; int cnt = 0;
#pragma unroll
      for (int slot = 0; slot < 9; ++slot) {
        bool ok = (slot < kD) ? (nts[n * kD + slot] <= tn) : true;
        if (ok) {
          unsigned u = pre1[(n * 9 + slot) * 64 + lane];
          float p0 = __uint_as_float(u << 16);
          float p1 = __uint_as_float(u & 0xffff0000u);
          s0 += fmaxf(fmaf(p0, sc.x, sh.x), 0.f);
          s1 += fmaxf(fmaf(p1, sc.y, sh.y), 0.f);
          cnt++;
        }
      }
      ag[q] = make_float2(s0 / (float)cnt, s1 / (float)cnt);
    }
    float acc[4] = {b2v, b2v, b2v, b2v};
#pragma unroll
    for (int kq = 0; kq < 32; ++kq) {
      float4 w = W2s[kq * 64 + lane];
#pragma unroll
      for (int q = 0; q < 4; ++q) {
        acc[q] += rl(ag[q].x, 2 * kq)     * w.x + rl(ag[q].y, 2 * kq)     * w.y
                + rl(ag[q].x, 2 * kq + 1) * w.z + rl(ag[q].y, 2 * kq + 1) * w.w;
      }
    }
#pragma unroll
    for (int q = 0; q < 4; ++q) {
      pre2[(n0 + q) * 64 + lane] = acc[q];
      ssum += acc[q]; ssq += acc[q] * acc[q];
    }
  }
  red[wave][lane] = make_float2(ssum, ssq);
  __syncthreads();
  if (wave == 0) {
    float s  = red[0][lane].x + red[1][lane].x + red[2][lane].x + red[3][lane].x;
    float q2 = red[0][lane].y + red[1][lane].y + red[2][lane].y + red[3][lane].y;
    atomicAdd(&stats[S_SUM2 + lane], s);
    atomicAdd(&stats[S_SQ2 + lane], q2);
  }
}

__global__ void k4_fin2(float* stats, const float* __restrict__ g2,
                        const float* __restrict__ be2) {
  int c = threadIdx.x;  // 64 threads
  float mean = stats[S_SUM2 + c] * (1.f / kN);
  float var  = stats[S_SQ2 + c] * (1.f / kN) - mean * mean;
  float sc   = g2[c] * rsqrtf(var + kEps);
  stats[P_SC2 + c] = sc;
  stats[P_SH2 + c] = be2[c] - mean * sc;
}

// K5: embs = relu(BN2(pre2)); embsW = embs * Wd  (decoder weight folded in)
__global__ __launch_bounds__(256) void k5_embs(
    const float* __restrict__ pre2, const float* __restrict__ stats,
    const float* __restrict__ Wd, float* __restrict__ embs,
    float* __restrict__ embsW)
{
  int idx = blockIdx.x * 256 + threadIdx.x;   // grid sized exactly kN*64/256
  int col = idx & 63;
  float e = fmaxf(fmaf(pre2[idx], stats[P_SC2 + col], stats[P_SH2 + col]), 0.f);
  embs[idx] = e;
  embsW[idx] = e * Wd[col];
}

// K6: thread-per-pair Hadamard dot + BCE, block tree-reduce, one atomic/block.
__global__ __launch_bounds__(256) void k6_loss(
    const float* __restrict__ embs, const float* __restrict__ embsW,
    const int* __restrict__ tgt, const int* __restrict__ neg,
    const float* __restrict__ bd, float* __restrict__ out)
{
  __shared__ float redl[256];
  int tid = threadIdx.x;
  int e = blockIdx.x * 256 + tid;
  float l = 0.f;
  if (e < 2 * kE) {
    int i, j; float lab;
    if (e < kE) { i = tgt[e];      j = tgt[kE + e]; lab = 1.f; }
    else        { i = neg[e - kE]; j = neg[e];      lab = 0.f; }
    const float4* a  = (const float4*)(embsW + (size_t)i * 64);
    const float4* bb = (const float4*)(embs  + (size_t)j * 64);
    float p = bd[0];
#pragma unroll
    for (int t = 0; t < 16; ++t) {
      float4 av = a[t], bv = bb[t];
      p += av.x * bv.x + av.y * bv.y + av.z * bv.z + av.w * bv.w;
    }
    l = fmaxf(p, 0.f) - p * lab + log1pf(expf(-fabsf(p)));
  }
  redl[tid] = l;
  __syncthreads();
  for (int s = 128; s > 0; s >>= 1) {
    if (tid < s) redl[tid] += redl[tid + s];
    __syncthreads();
  }
  if (tid == 0) atomicAdd(out, redl[0] * (1.f / (2 * kE)));
}

extern "C" void kernel_launch(void* const* d_in, const int* in_sizes, int n_in,
                              void* d_out, int out_size, void* d_ws, size_t ws_size,
                              hipStream_t stream) {
  (void)in_sizes; (void)n_in; (void)out_size; (void)ws_size;
  const float* x       = (const float*)d_in[0];
  const float* node_ts = (const float*)d_in[1];
  const int*   nidx    = (const int*)d_in[2];
  const float* nts     = (const float*)d_in[3];
  const int*   tgt     = (const int*)d_in[4];
  const int*   neg     = (const int*)d_in[5];
  const float* W1      = (const float*)d_in[6];
  const float* b1      = (const float*)d_in[7];
  const float* g1      = (const float*)d_in[8];
  const float* be1     = (const float*)d_in[9];
  const float* W2      = (const float*)d_in[10];
  const float* b2      = (const float*)d_in[11];
  const float* g2      = (const float*)d_in[12];
  const float* be2     = (const float*)d_in[13];
  const float* Wd      = (const float*)d_in[14];
  const float* bd      = (const float*)d_in[15];

  char* ws = (char*)d_ws;
  unsigned* pre1 = (unsigned*)ws;                     // bf16x2 [kM][64]
  float* pre2  = (float*)(ws + OFF_PRE2);
  float* embs  = (float*)(ws + OFF_EMBS);
  float* embsW = (float*)(ws + OFF_EMBSW);
  float* stats = (float*)(ws + OFF_STATS);
  float* out   = (float*)d_out;

  hipMemsetAsync(stats, 0, 384 * sizeof(float), stream);
  hipMemsetAsync(out, 0, sizeof(float), stream);

  k1_agg_gemm1<<<1024, 256, 0, stream>>>(x, node_ts, nidx, nts, W1, b1, pre1, stats);
  k2_fin1<<<1, 128, 0, stream>>>(stats, g1, be1);
  k3_agg_gemm2<<<625, 256, 0, stream>>>(pre1, node_ts, nts, W2, b2, stats, pre2);
  k4_fin2<<<1, 64, 0, stream>>>(stats, g2, be2);
  k5_embs<<<kN * 64 / 256, 256, 0, stream>>>(pre2, stats, Wd, embs, embsW);
  k6_loss<<<(2 * kE + 255) / 256, 256, 0, stream>>>(embs, embsW, tgt, neg, bd, out);
}

// Round 2
// 249.206 us; speedup vs baseline: 4.2520x; 4.2520x over previous
//
#include <hip/hip_runtime.h>
#include <math.h>

constexpr int kN = 20000;
constexpr int kD = 8;
constexpr int kE = 100000;
constexpr int kM = kN * 9;            // 180000 level-1 rows
constexpr int kTiles1 = kM / 16;      // 11250 MFMA row-tiles (exact)
constexpr int kTiles3 = kN / 16;      // 1250
constexpr float kEps = 1e-5f;

// stats/params layout (float indices) inside ws stats block
constexpr int S_SUM1 = 0, S_SQ1 = 128, S_SUM2 = 256, S_SQ2 = 320;
constexpr int P_SC1 = 384, P_SH1 = 512, P_SC2 = 640, P_SH2 = 704;

// ws byte offsets
constexpr size_t OFF_AGG2  = 46080000;   // after pre1 bf16 [kM][128]
constexpr size_t OFF_PRE2  = 51200000;
constexpr size_t OFF_EMBS  = 56320000;
constexpr size_t OFF_STATS = 61440000;

typedef short short8 __attribute__((ext_vector_type(8)));
typedef float floatx4 __attribute__((ext_vector_type(4)));

__device__ __forceinline__ unsigned f2bf(float f) {  // f32 -> bf16 (RNE)
  unsigned u = __float_as_uint(f);
  u += 0x7fffu + ((u >> 16) & 1u);
  return u >> 16;
}

// ---------------------------------------------------------------------------
// K1: level-1 gather + masked mean -> per-wave LDS A-tile (bf16) ->
//     MFMA GEMM1 (16 rows x 128 cols per wave, K=64) + bias -> pre1 bf16,
//     BN1 sum/sumsq per lane, block LDS reduce, one atomic per column.
// Frag layouts (guide-verified): A/B [m|n=lane&15][k=(lane>>4)*8+j],
//                                C/D col=lane&15, row=(lane>>4)*4+reg.
// ---------------------------------------------------------------------------
__global__ __launch_bounds__(256, 3) void k1_gather_gemm1(
    const float* __restrict__ x, const float* __restrict__ node_ts,
    const int* __restrict__ nidx, const float* __restrict__ nts,
    const float* __restrict__ W1, const float* __restrict__ b1,
    unsigned short* __restrict__ pre1,   // bf16 [kM][128] row-major
    float* __restrict__ stats)
{
  __shared__ unsigned short W1T[128 * 64];     // [n][k] bf16, 16 KB
  __shared__ unsigned short atile[4][16 * 64]; // per-wave A staging, 8 KB
  __shared__ float redS[256][8];               // 8 KB
  __shared__ float redQ[256][8];               // 8 KB

  const int tid = threadIdx.x;
  const int lane = tid & 63;
  const int wave = tid >> 6;
  const int l15 = lane & 15;
  const int q = lane >> 4;

  // stage W1^T bf16 into LDS: W1T[n*64+k] = W1[k][n] (W1 is [64][128])
  for (int i = tid; i < 8192; i += 256) {
    int n = i >> 6, k = i & 63;
    W1T[i] = (unsigned short)f2bf(W1[k * 128 + n]);
  }
  __syncthreads();

  // B fragments: col-tile c (8), k-step s (2): B[n=c*16+l15][k=q*8+j+32s]
  short8 bf[8][2];
#pragma unroll
  for (int c = 0; c < 8; ++c)
#pragma unroll
    for (int s = 0; s < 2; ++s)
      bf[c][s] = *(const short8*)&W1T[(c * 16 + l15) * 64 + q * 8 + s * 32];

  float b1c[8];
#pragma unroll
  for (int c = 0; c < 8; ++c) b1c[c] = b1[c * 16 + l15];

  float sum8[8], sq8[8];
#pragma unroll
  for (int c = 0; c < 8; ++c) { sum8[c] = 0.f; sq8[c] = 0.f; }

  const int gw = blockIdx.x * 4 + wave;
  const int nw = gridDim.x * 4;

  for (int t = gw; t < kTiles1; t += nw) {
    const int r0 = t * 16;
    // ---- gather 16 rows, lane = feature, straight-line mask-multiply ----
#pragma unroll 2
    for (int r = 0; r < 16; ++r) {
      int m = r0 + r;
      int n = (int)((unsigned)m / 9u);
      int slot = m - n * 9;
      int c; float tt;
      if (slot < kD) { c = nidx[n * kD + slot]; tt = nts[n * kD + slot]; }
      else           { c = n;                   tt = node_ts[n]; }
      float s = x[c * 64 + lane];
      float fcnt = 1.f;
#pragma unroll
      for (int j = 0; j < kD; ++j) {
        float w = (nts[c * kD + j] <= tt) ? 1.f : 0.f;
        s = fmaf(w, x[nidx[c * kD + j] * 64 + lane], s);
        fcnt += w;
      }
      atile[wave][r * 64 + lane] = (unsigned short)f2bf(s / fcnt);
    }
    // ---- A fragments (same-wave LDS produce->consume; HW waitcnt) ----
    short8 af0 = *(const short8*)&atile[wave][l15 * 64 + q * 8];
    short8 af1 = *(const short8*)&atile[wave][l15 * 64 + q * 8 + 32];

    floatx4 acc[8];
#pragma unroll
    for (int c = 0; c < 8; ++c) {
      acc[c] = (floatx4){0.f, 0.f, 0.f, 0.f};
      acc[c] = __builtin_amdgcn_mfma_f32_16x16x32_bf16(af0, bf[c][0], acc[c], 0, 0, 0);
      acc[c] = __builtin_amdgcn_mfma_f32_16x16x32_bf16(af1, bf[c][1], acc[c], 0, 0, 0);
    }
    // ---- epilogue: bias, bf16 store, BN1 partial stats ----
#pragma unroll
    for (int c = 0; c < 8; ++c) {
      int col = c * 16 + l15;
#pragma unroll
      for (int i = 0; i < 4; ++i) {
        float v = acc[c][i] + b1c[c];
        int row = r0 + q * 4 + i;
        pre1[row * 128 + col] = (unsigned short)f2bf(v);
        sum8[c] += v; sq8[c] += v * v;
      }
    }
  }

  __syncthreads();
#pragma unroll
  for (int c = 0; c < 8; ++c) { redS[tid][c] = sum8[c]; redQ[tid][c] = sq8[c]; }
  __syncthreads();
  if (tid < 128) {
    int c = tid >> 4, r15 = tid & 15;
    float s = 0.f, qq = 0.f;
#pragma unroll
    for (int w = 0; w < 4; ++w)
#pragma unroll
      for (int p = 0; p < 4; ++p) {
        int T = w * 64 + p * 16 + r15;
        s += redS[T][c]; qq += redQ[T][c];
      }
    atomicAdd(&stats[S_SUM1 + tid], s);
    atomicAdd(&stats[S_SQ1 + tid], qq);
  }
}

__global__ void k2_fin1(float* stats, const float* __restrict__ g1,
                        const float* __restrict__ be1) {
  int c = threadIdx.x;  // 128 threads
  float mean = stats[S_SUM1 + c] * (1.f / kM);
  float var  = stats[S_SQ1 + c] * (1.f / kM) - mean * mean;
  float sc   = g1[c] * rsqrtf(var + kEps);
  stats[P_SC1 + c] = sc;
  stats[P_SH1 + c] = be1[c] - mean * sc;
}

// ---------------------------------------------------------------------------
// K3a: BN1+ReLU on pre1 + masked mean over 9 child slots -> agg2 bf16 [N][128]
// One wave per node; lane handles col pair (2L, 2L+1) via dword reads of pre1.
// ---------------------------------------------------------------------------
__global__ __launch_bounds__(256) void k3a_agg2(
    const unsigned* __restrict__ pre1dw, const float* __restrict__ node_ts,
    const float* __restrict__ nts, const float* __restrict__ stats,
    unsigned* __restrict__ agg2dw)
{
  const int n = blockIdx.x * 4 + (threadIdx.x >> 6);  // grid exact kN/4
  const int L = threadIdx.x & 63;
  const float sc0 = stats[P_SC1 + 2 * L], sc1 = stats[P_SC1 + 2 * L + 1];
  const float sh0 = stats[P_SH1 + 2 * L], sh1 = stats[P_SH1 + 2 * L + 1];
  const float tn = node_ts[n];
  float s0 = 0.f, s1 = 0.f, fcnt = 0.f;
#pragma unroll
  for (int slot = 0; slot < 9; ++slot) {
    float w = (slot < kD) ? ((nts[n * kD + slot] <= tn) ? 1.f : 0.f) : 1.f;
    unsigned u = pre1dw[(n * 9 + slot) * 64 + L];
    float p0 = __uint_as_float(u << 16);
    float p1 = __uint_as_float(u & 0xffff0000u);
    s0 += w * fmaxf(fmaf(p0, sc0, sh0), 0.f);
    s1 += w * fmaxf(fmaf(p1, sc1, sh1), 0.f);
    fcnt += w;
  }
  float r = 1.f / fcnt;
  agg2dw[n * 64 + L] = f2bf(s0 * r) | (f2bf(s1 * r) << 16);
}

// ---------------------------------------------------------------------------
// K3b: MFMA GEMM2: agg2 [N][128] bf16 x W2 [128][64] + b2 -> pre2 f32 [N][64],
//      BN2 sum/sumsq. 16 rows x 64 cols per wave, K=128 (4 k-steps).
// ---------------------------------------------------------------------------
__global__ __launch_bounds__(256, 3) void k3b_gemm2(
    const unsigned short* __restrict__ agg2, const float* __restrict__ W2,
    const float* __restrict__ b2, float* __restrict__ stats,
    float* __restrict__ pre2)
{
  __shared__ unsigned short W2T[64 * 128];   // [n][k] bf16, 16 KB
  __shared__ float redS[256][4];
  __shared__ float redQ[256][4];

  const int tid = threadIdx.x;
  const int lane = tid & 63;
  const int wave = tid >> 6;
  const int l15 = lane & 15;
  const int q = lane >> 4;

  for (int i = tid; i < 8192; i += 256) {
    int n = i >> 7, k = i & 127;
    W2T[i] = (unsigned short)f2bf(W2[k * 64 + n]);
  }
  __syncthreads();

  short8 bfr[4][4];
#pragma unroll
  for (int c = 0; c < 4; ++c)
#pragma unroll
    for (int s = 0; s < 4; ++s)
      bfr[c][s] = *(const short8*)&W2T[(c * 16 + l15) * 128 + q * 8 + s * 32];

  float b2c[4];
#pragma unroll
  for (int c = 0; c < 4; ++c) b2c[c] = b2[c * 16 + l15];

  float sum4[4], sq4[4];
#pragma unroll
  for (int c = 0; c < 4; ++c) { sum4[c] = 0.f; sq4[c] = 0.f; }

  const int gw = blockIdx.x * 4 + wave;
  const int nw = gridDim.x * 4;

  for (int t = gw; t < kTiles3; t += nw) {
    const int r0 = t * 16;
    short8 af[4];
#pragma unroll
    for (int s = 0; s < 4; ++s)
      af[s] = *(const short8*)&agg2[(r0 + l15) * 128 + q * 8 + s * 32];

    floatx4 acc[4];
#pragma unroll
    for (int c = 0; c < 4; ++c) {
      acc[c] = (floatx4){0.f, 0.f, 0.f, 0.f};
#pragma unroll
      for (int s = 0; s < 4; ++s)
        acc[c] = __builtin_amdgcn_mfma_f32_16x16x32_bf16(af[s], bfr[c][s], acc[c], 0, 0, 0);
    }
#pragma unroll
    for (int c = 0; c < 4; ++c) {
      int col = c * 16 + l15;
#pragma unroll
      for (int i = 0; i < 4; ++i) {
        float v = acc[c][i] + b2c[c];
        int row = r0 + q * 4 + i;
        pre2[row * 64 + col] = v;
        sum4[c] += v; sq4[c] += v * v;
      }
    }
  }

  __syncthreads();
#pragma unroll
  for (int c = 0; c < 4; ++c) { redS[tid][c] = sum4[c]; redQ[tid][c] = sq4[c]; }
  __syncthreads();
  if (tid < 64) {
    int c = tid >> 4, r15 = tid & 15;
    float s = 0.f, qq = 0.f;
#pragma unroll
    for (int w = 0; w < 4; ++w)
#pragma unroll
      for (int p = 0; p < 4; ++p) {
        int T = w * 64 + p * 16 + r15;
        s += redS[T][c]; qq += redQ[T][c];
      }
    atomicAdd(&stats[S_SUM2 + tid], s);
    atomicAdd(&stats[S_SQ2 + tid], qq);
  }
}

__global__ void k4_fin2(float* stats, const float* __restrict__ g2,
                        const float* __restrict__ be2) {
  int c = threadIdx.x;  // 64 threads
  float mean = stats[S_SUM2 + c] * (1.f / kN);
  float var  = stats[S_SQ2 + c] * (1.f / kN) - mean * mean;
  float sc   = g2[c] * rsqrtf(var + kEps);
  stats[P_SC2 + c] = sc;
  stats[P_SH2 + c] = be2[c] - mean * sc;
}

// K5: embs = relu(BN2(pre2))
__global__ __launch_bounds__(256) void k5_embs(
    const float* __restrict__ pre2, const float* __restrict__ stats,
    float* __restrict__ embs)
{
  int idx = blockIdx.x * 256 + threadIdx.x;   // grid exact kN*64/256
  int col = idx & 63;
  embs[idx] = fmaxf(fmaf(pre2[idx], stats[P_SC2 + col], stats[P_SH2 + col]), 0.f);
}

// K6: thread-per-pair weighted Hadamard dot + BCE, block reduce, atomic.
__global__ __launch_bounds__(256) void k6_loss(
    const float* __restrict__ embs, const int* __restrict__ tgt,
    const int* __restrict__ neg, const float* __restrict__ Wd,
    const float* __restrict__ bd, float* __restrict__ out)
{
  __shared__ float wds[64];
  __shared__ float redl[256];
  int tid = threadIdx.x;
  if (tid < 64) wds[tid] = Wd[tid];
  __syncthreads();
  int e = blockIdx.x * 256 + tid;
  float l = 0.f;
  if (e < 2 * kE) {
    int i, j; float lab;
    if (e < kE) { i = tgt[e];      j = tgt[kE + e]; lab = 1.f; }
    else        { i = neg[e - kE]; j = neg[e];      lab = 0.f; }
    const float4* a  = (const float4*)(embs + (size_t)i * 64);
    const float4* bb = (const float4*)(embs + (size_t)j * 64);
    const float4* wv = (const float4*)wds;
    float p = bd[0];
#pragma unroll
    for (int t = 0; t < 16; ++t) {
      float4 av = a[t], bv = bb[t], w4 = wv[t];
      p += (av.x * bv.x) * w4.x + (av.y * bv.y) * w4.y
         + (av.z * bv.z) * w4.z + (av.w * bv.w) * w4.w;
    }
    l = fmaxf(p, 0.f) - p * lab + log1pf(expf(-fabsf(p)));
  }
  redl[tid] = l;
  __syncthreads();
  for (int s = 128; s > 0; s >>= 1) {
    if (tid < s) redl[tid] += redl[tid + s];
    __syncthreads();
  }
  if (tid == 0) atomicAdd(out, redl[0] * (1.f / (2 * kE)));
}

extern "C" void kernel_launch(void* const* d_in, const int* in_sizes, int n_in,
                              void* d_out, int out_size, void* d_ws, size_t ws_size,
                              hipStream_t stream) {
  (void)in_sizes; (void)n_in; (void)out_size; (void)ws_size;
  const float* x       = (const float*)d_in[0];
  const float* node_ts = (const float*)d_in[1];
  const int*   nidx    = (const int*)d_in[2];
  const float* nts     = (const float*)d_in[3];
  const int*   tgt     = (const int*)d_in[4];
  const int*   neg     = (const int*)d_in[5];
  const float* W1      = (const float*)d_in[6];
  const float* b1      = (const float*)d_in[7];
  const float* g1      = (const float*)d_in[8];
  const float* be1     = (const float*)d_in[9];
  const float* W2      = (const float*)d_in[10];
  const float* b2      = (const float*)d_in[11];
  const float* g2      = (const float*)d_in[12];
  const float* be2     = (const float*)d_in[13];
  const float* Wd      = (const float*)d_in[14];
  const float* bd      = (const float*)d_in[15];

  char* ws = (char*)d_ws;
  unsigned short* pre1 = (unsigned short*)ws;          // bf16 [kM][128]
  unsigned short* agg2 = (unsigned short*)(ws + OFF_AGG2); // bf16 [kN][128]
  float* pre2  = (float*)(ws + OFF_PRE2);
  float* embs  = (float*)(ws + OFF_EMBS);
  float* stats = (float*)(ws + OFF_STATS);
  float* out   = (float*)d_out;

  hipMemsetAsync(stats, 0, 384 * sizeof(float), stream);
  hipMemsetAsync(out, 0, sizeof(float), stream);

  k1_gather_gemm1<<<1408, 256, 0, stream>>>(x, node_ts, nidx, nts, W1, b1, pre1, stats);
  k2_fin1<<<1, 128, 0, stream>>>(stats, g1, be1);
  k3a_agg2<<<kN / 4, 256, 0, stream>>>((const unsigned*)pre1, node_ts, nts, stats,
                                       (unsigned*)agg2);
  k3b_gemm2<<<160, 256, 0, stream>>>(agg2, W2, b2, stats, pre2);
  k4_fin2<<<1, 64, 0, stream>>>(stats, g2, be2);
  k5_embs<<<kN * 64 / 256, 256, 0, stream>>>(pre2, stats, embs);
  k6_loss<<<(2 * kE + 255) / 256, 256, 0, stream>>>(embs, tgt, neg, Wd, bd, out);
}

// Round 3
// 220.800 us; speedup vs baseline: 4.7990x; 1.1287x over previous
//
#include <hip/hip_runtime.h>
#include <math.h>

constexpr int kN = 20000;
constexpr int kD = 8;
constexpr int kE = 100000;
constexpr int kM = kN * 9;            // 180000 level-1 rows
constexpr int kTiles1 = kM / 16;      // 11250
constexpr int kTiles3 = kN / 16;      // 1250
constexpr float kEps = 1e-5f;

// stats float indices
constexpr int S_SUM1 = 0, S_SQ1 = 128, S_SUM2 = 256, S_SQ2 = 320;

// ws layout (bytes). Peak live = 51.2 MB (< proven 61.5 MB from R1/R2).
// Region A [0,23.04M): agg1 (frag-layout bf16) -> overwritten in-place by
//   k1b with pre1 cols 0..63 (row-major bf16) -> dead after k3a -> reused
//   for pre2/embs/embsW.
// Region B [23.04M,46.08M): pre1 cols 64..127.
constexpr size_t REG_B     = 23040000;
constexpr size_t OFF_AGG2  = 46080000;   // bf16 [kN][128] = 5.12 MB
constexpr size_t OFF_STATS = 51200000;   // 384 floats
constexpr size_t OFF_PRE2  = 0;          // f32 [kN][64] = 5.12 MB (reuse A)
constexpr size_t OFF_EMBS  = 5120000;
constexpr size_t OFF_EMBSW = 10240000;

typedef short short8 __attribute__((ext_vector_type(8)));
typedef float floatx4 __attribute__((ext_vector_type(4)));

__device__ __forceinline__ unsigned f2bf(float f) {  // f32 -> bf16 (RNE)
  unsigned u = __float_as_uint(f);
  u += 0x7fffu + ((u >> 16) & 1u);
  return u >> 16;
}

// ---------------------------------------------------------------------------
// K1a: one wave per level-1 row m. lane = feature. Gather 9 x-rows (masked
// mean) and store agg1 bf16 in MFMA A-FRAGMENT order:
//   addr(m,k) = (m/16)*1024 + (k/8)*128 + (m%16)*8 + (k%8)   [shorts]
// so k1b can read A-frags as coalesced 16B/lane global loads.
// 180k independent waves -> latency fully hidden by TLP.
// ---------------------------------------------------------------------------
__global__ __launch_bounds__(256) void k1a_gather(
    const float* __restrict__ x, const float* __restrict__ node_ts,
    const int* __restrict__ nidx, const float* __restrict__ nts,
    unsigned short* __restrict__ agg1)
{
  const int m = blockIdx.x * 4 + (threadIdx.x >> 6);
  const int lane = threadIdx.x & 63;
  const int n = (int)((unsigned)m / 9u);
  const int slot = m - n * 9;
  int c; float t;
  if (slot < kD) { c = nidx[n * kD + slot]; t = nts[n * kD + slot]; }
  else           { c = n;                   t = node_ts[n]; }
  c = __builtin_amdgcn_readfirstlane(c);
  float s = x[c * 64 + lane];
  float fcnt = 1.f;
#pragma unroll
  for (int j = 0; j < kD; ++j) {
    int cj = nidx[c * kD + j];
    float w = (nts[c * kD + j] <= t) ? 1.f : 0.f;
    s = fmaf(w, x[cj * 64 + lane], s);
    fcnt += w;
  }
  float v = s / fcnt;
  const int tt = m >> 4, r = m & 15, g = lane >> 3, jj = lane & 7;
  agg1[tt * 1024 + g * 128 + r * 8 + jj] = (unsigned short)f2bf(v);
}

// ---------------------------------------------------------------------------
// K1b: MFMA GEMM1. Wave per 16-row tile, A-frags straight from global
// (frag-ordered agg1, coalesced), B (W1^T) in padded LDS (stride 72 shorts
// -> 2-way bank alias = free). Stores pre1 split: cols 0..63 overwrite the
// tile's own agg1 (safe: stores data-depend on A-frag loads via MFMA),
// cols 64..127 to region B. BN1 sum/sumsq block-reduced, atomic per column.
// ---------------------------------------------------------------------------
__global__ __launch_bounds__(256, 3) void k1b_gemm1(
    const unsigned short* aggA,          // region A, frag layout (aliases preLo)
    unsigned short* preLo,               // region A, rows x cols0..63 row-major
    unsigned short* __restrict__ preHi,  // region B, rows x cols64..127
    const float* __restrict__ W1, const float* __restrict__ b1,
    float* __restrict__ stats)
{
  __shared__ unsigned short W1T[128 * 72];   // padded: l15*36 dw -> 2-way, free
  __shared__ float redS[256][8];
  __shared__ float redQ[256][8];

  const int tid = threadIdx.x;
  const int lane = tid & 63;
  const int wave = tid >> 6;
  const int l15 = lane & 15;
  const int q = lane >> 4;

  for (int i = tid; i < 8192; i += 256) {
    int n = i >> 6, k = i & 63;
    W1T[n * 72 + k] = (unsigned short)f2bf(W1[k * 128 + n]);
  }
  __syncthreads();

  short8 bf[8][2];
#pragma unroll
  for (int c = 0; c < 8; ++c)
#pragma unroll
    for (int s = 0; s < 2; ++s)
      bf[c][s] = *(const short8*)&W1T[(c * 16 + l15) * 72 + q * 8 + s * 32];

  float b1c[8];
#pragma unroll
  for (int c = 0; c < 8; ++c) b1c[c] = b1[c * 16 + l15];

  float sum8[8], sq8[8];
#pragma unroll
  for (int c = 0; c < 8; ++c) { sum8[c] = 0.f; sq8[c] = 0.f; }

  const int gw = blockIdx.x * 4 + wave;
  const int nw = gridDim.x * 4;

  for (int t = gw; t < kTiles1; t += nw) {
    const unsigned short* ap = aggA + (size_t)t * 1024;
    short8 af0 = *(const short8*)(ap + (q)*128 + l15 * 8);          // k in [0,32)
    short8 af1 = *(const short8*)(ap + (4 + q) * 128 + l15 * 8);    // k in [32,64)

    floatx4 acc[8];
#pragma unroll
    for (int c = 0; c < 8; ++c) {
      acc[c] = (floatx4){0.f, 0.f, 0.f, 0.f};
      acc[c] = __builtin_amdgcn_mfma_f32_16x16x32_bf16(af0, bf[c][0], acc[c], 0, 0, 0);
      acc[c] = __builtin_amdgcn_mfma_f32_16x16x32_bf16(af1, bf[c][1], acc[c], 0, 0, 0);
    }
#pragma unroll
    for (int c = 0; c < 8; ++c) {
      int colq = (c & 3) * 16 + l15;     // col within its 64-wide half
#pragma unroll
      for (int i = 0; i < 4; ++i) {
        float v = acc[c][i] + b1c[c];
        int row = t * 16 + q * 4 + i;
        unsigned short hv = (unsigned short)f2bf(v);
        if (c < 4) preLo[(size_t)row * 64 + colq] = hv;
        else       preHi[(size_t)row * 64 + colq] = hv;
        sum8[c] += v; sq8[c] += v * v;
      }
    }
  }

  __syncthreads();
#pragma unroll
  for (int c = 0; c < 8; ++c) { redS[tid][c] = sum8[c]; redQ[tid][c] = sq8[c]; }
  __syncthreads();
  if (tid < 128) {
    int c = tid >> 4, r15 = tid & 15;
    float s = 0.f, qq = 0.f;
#pragma unroll
    for (int w = 0; w < 4; ++w)
#pragma unroll
      for (int p = 0; p < 4; ++p) {
        int T = w * 64 + p * 16 + r15;
        s += redS[T][c]; qq += redQ[T][c];
      }
    atomicAdd(&stats[S_SUM1 + tid], s);
    atomicAdd(&stats[S_SQ1 + tid], qq);
  }
}

// ---------------------------------------------------------------------------
// K3a: (BN1 finalize folded in) BN1+ReLU on split pre1, masked mean over 9
// slots -> agg2 bf16 [kN][128] row-major. One wave per node, lane = col pair.
// ---------------------------------------------------------------------------
__global__ __launch_bounds__(256) void k3a_agg2(
    const unsigned* __restrict__ loDW, const unsigned* __restrict__ hiDW,
    const float* __restrict__ node_ts, const float* __restrict__ nts,
    const float* __restrict__ stats, const float* __restrict__ g1,
    const float* __restrict__ be1, unsigned* __restrict__ agg2dw)
{
  __shared__ float sc[128], sh[128];
  const int tid = threadIdx.x;
  if (tid < 128) {
    float mean = stats[S_SUM1 + tid] * (1.f / kM);
    float var  = stats[S_SQ1 + tid] * (1.f / kM) - mean * mean;
    float s    = g1[tid] * rsqrtf(var + kEps);
    sc[tid] = s; sh[tid] = be1[tid] - mean * s;
  }
  __syncthreads();
  const int n = blockIdx.x * 4 + (tid >> 6);
  const int L = tid & 63;
  const unsigned* base = (L < 32) ? loDW : hiDW;
  const int Lc = L & 31;
  const float sc0 = sc[2 * L], sc1 = sc[2 * L + 1];
  const float sh0 = sh[2 * L], sh1 = sh[2 * L + 1];
  const float tn = node_ts[n];
  float s0 = 0.f, s1 = 0.f, fcnt = 0.f;
#pragma unroll
  for (int slot = 0; slot < 9; ++slot) {
    float w = (slot < kD) ? ((nts[n * kD + slot] <= tn) ? 1.f : 0.f) : 1.f;
    unsigned u = base[(size_t)(n * 9 + slot) * 32 + Lc];
    float p0 = __uint_as_float(u << 16);
    float p1 = __uint_as_float(u & 0xffff0000u);
    s0 += w * fmaxf(fmaf(p0, sc0, sh0), 0.f);
    s1 += w * fmaxf(fmaf(p1, sc1, sh1), 0.f);
    fcnt += w;
  }
  float r = 1.f / fcnt;
  agg2dw[n * 64 + L] = f2bf(s0 * r) | (f2bf(s1 * r) << 16);
}

// ---------------------------------------------------------------------------
// K3b: MFMA GEMM2: agg2 [N][128] x W2 [128][64] + b2 -> pre2 f32, BN2 stats.
// ---------------------------------------------------------------------------
__global__ __launch_bounds__(256, 3) void k3b_gemm2(
    const unsigned short* __restrict__ agg2, const float* __restrict__ W2,
    const float* __restrict__ b2, float* __restrict__ stats,
    float* __restrict__ pre2)
{
  __shared__ unsigned short W2T[64 * 136];   // padded leading dim
  __shared__ float redS[256][4];
  __shared__ float redQ[256][4];

  const int tid = threadIdx.x;
  const int lane = tid & 63;
  const int wave = tid >> 6;
  const int l15 = lane & 15;
  const int q = lane >> 4;

  for (int i = tid; i < 8192; i += 256) {
    int n = i >> 7, k = i & 127;
    W2T[n * 136 + k] = (unsigned short)f2bf(W2[k * 64 + n]);
  }
  __syncthreads();

  short8 bfr[4][4];
#pragma unroll
  for (int c = 0; c < 4; ++c)
#pragma unroll
    for (int s = 0; s < 4; ++s)
      bfr[c][s] = *(const short8*)&W2T[(c * 16 + l15) * 136 + q * 8 + s * 32];

  float b2c[4];
#pragma unroll
  for (int c = 0; c < 4; ++c) b2c[c] = b2[c * 16 + l15];

  float sum4[4], sq4[4];
#pragma unroll
  for (int c = 0; c < 4; ++c) { sum4[c] = 0.f; sq4[c] = 0.f; }

  const int gw = blockIdx.x * 4 + wave;
  const int nw = gridDim.x * 4;

  for (int t = gw; t < kTiles3; t += nw) {
    const int r0 = t * 16;
    short8 af[4];
#pragma unroll
    for (int s = 0; s < 4; ++s)
      af[s] = *(const short8*)&agg2[(size_t)(r0 + l15) * 128 + q * 8 + s * 32];

    floatx4 acc[4];
#pragma unroll
    for (int c = 0; c < 4; ++c) {
      acc[c] = (floatx4){0.f, 0.f, 0.f, 0.f};
#pragma unroll
      for (int s = 0; s < 4; ++s)
        acc[c] = __builtin_amdgcn_mfma_f32_16x16x32_bf16(af[s], bfr[c][s], acc[c], 0, 0, 0);
    }
#pragma unroll
    for (int c = 0; c < 4; ++c) {
      int col = c * 16 + l15;
#pragma unroll
      for (int i = 0; i < 4; ++i) {
        float v = acc[c][i] + b2c[c];
        int row = r0 + q * 4 + i;
        pre2[(size_t)row * 64 + col] = v;
        sum4[c] += v; sq4[c] += v * v;
      }
    }
  }

  __syncthreads();
#pragma unroll
  for (int c = 0; c < 4; ++c) { redS[tid][c] = sum4[c]; redQ[tid][c] = sq4[c]; }
  __syncthreads();
  if (tid < 64) {
    int c = tid >> 4, r15 = tid & 15;
    float s = 0.f, qq = 0.f;
#pragma unroll
    for (int w = 0; w < 4; ++w)
#pragma unroll
      for (int p = 0; p < 4; ++p) {
        int T = w * 64 + p * 16 + r15;
        s += redS[T][c]; qq += redQ[T][c];
      }
    atomicAdd(&stats[S_SUM2 + tid], s);
    atomicAdd(&stats[S_SQ2 + tid], qq);
  }
}

// K5: (BN2 finalize folded in) embs = relu(BN2(pre2)); embsW = embs * Wd.
__global__ __launch_bounds__(256) void k5_embs(
    const float* __restrict__ pre2, const float* __restrict__ stats,
    const float* __restrict__ g2, const float* __restrict__ be2,
    const float* __restrict__ Wd, float* __restrict__ embs,
    float* __restrict__ embsW)
{
  __shared__ float sc[64], sh[64], wd[64];
  const int tid = threadIdx.x;
  if (tid < 64) {
    float mean = stats[S_SUM2 + tid] * (1.f / kN);
    float var  = stats[S_SQ2 + tid] * (1.f / kN) - mean * mean;
    float s    = g2[tid] * rsqrtf(var + kEps);
    sc[tid] = s; sh[tid] = be2[tid] - mean * s; wd[tid] = Wd[tid];
  }
  __syncthreads();
  int idx = blockIdx.x * 256 + tid;   // grid exact kN*64/256
  int col = idx & 63;
  float e = fmaxf(fmaf(pre2[idx], sc[col], sh[col]), 0.f);
  embs[idx] = e;
  embsW[idx] = e * wd[col];
}

// K6: quarter-wave (16 lanes) per pair, 8 pairs per quarter. Coalesced 256B
// row reads, shfl_xor butterfly dot-reduce, block LDS reduce, one atomic.
__global__ __launch_bounds__(256) void k6_loss(
    const float* __restrict__ embs, const float* __restrict__ embsW,
    const int* __restrict__ tgt, const int* __restrict__ neg,
    const float* __restrict__ bd, float* __restrict__ out)
{
  __shared__ float redl[256];
  const int tid = threadIdx.x;
  const int tq = tid & 15;
  const int qb = tid >> 4;           // 16 quarters per block
  const float bd0 = bd[0];
  float lsum = 0.f;
  const int e0 = blockIdx.x * 128 + qb * 8;
#pragma unroll
  for (int it = 0; it < 8; ++it) {
    int e = e0 + it;
    if (e < 2 * kE) {
      int i, j; float lab;
      if (e < kE) { i = tgt[e];      j = tgt[kE + e]; lab = 1.f; }
      else        { i = neg[e - kE]; j = neg[e];      lab = 0.f; }
      float4 av = *(const float4*)(embsW + (size_t)i * 64 + tq * 4);
      float4 bv = *(const float4*)(embs  + (size_t)j * 64 + tq * 4);
      float p = av.x * bv.x + av.y * bv.y + av.z * bv.z + av.w * bv.w;
      p += __shfl_xor(p, 1); p += __shfl_xor(p, 2);
      p += __shfl_xor(p, 4); p += __shfl_xor(p, 8);
      p += bd0;
      float l = fmaxf(p, 0.f) - p * lab + log1pf(expf(-fabsf(p)));
      if (tq == 0) lsum += l;
    }
  }
  redl[tid] = lsum;
  __syncthreads();
  for (int s = 128; s > 0; s >>= 1) {
    if (tid < s) redl[tid] += redl[tid + s];
    __syncthreads();
  }
  if (tid == 0) atomicAdd(out, redl[0] * (1.f / (2 * kE)));
}

extern "C" void kernel_launch(void* const* d_in, const int* in_sizes, int n_in,
                              void* d_out, int out_size, void* d_ws, size_t ws_size,
                              hipStream_t stream) {
  (void)in_sizes; (void)n_in; (void)out_size; (void)ws_size;
  const float* x       = (const float*)d_in[0];
  const float* node_ts = (const float*)d_in[1];
  const int*   nidx    = (const int*)d_in[2];
  const float* nts     = (const float*)d_in[3];
  const int*   tgt     = (const int*)d_in[4];
  const int*   neg     = (const int*)d_in[5];
  const float* W1      = (const float*)d_in[6];
  const float* b1      = (const float*)d_in[7];
  const float* g1      = (const float*)d_in[8];
  const float* be1     = (const float*)d_in[9];
  const float* W2      = (const float*)d_in[10];
  const float* b2      = (const float*)d_in[11];
  const float* g2      = (const float*)d_in[12];
  const float* be2     = (const float*)d_in[13];
  const float* Wd      = (const float*)d_in[14];
  const float* bd      = (const float*)d_in[15];

  char* ws = (char*)d_ws;
  unsigned short* regA  = (unsigned short*)ws;             // agg1 frag / preLo
  unsigned short* regB  = (unsigned short*)(ws + REG_B);   // preHi
  unsigned short* agg2  = (unsigned short*)(ws + OFF_AGG2);
  float* stats = (float*)(ws + OFF_STATS);
  float* pre2  = (float*)(ws + OFF_PRE2);
  float* embs  = (float*)(ws + OFF_EMBS);
  float* embsW = (float*)(ws + OFF_EMBSW);
  float* out   = (float*)d_out;

  hipMemsetAsync(stats, 0, 384 * sizeof(float), stream);
  hipMemsetAsync(out, 0, sizeof(float), stream);

  k1a_gather<<<kM / 4, 256, 0, stream>>>(x, node_ts, nidx, nts, regA);
  k1b_gemm1<<<704, 256, 0, stream>>>(regA, regA, regB, W1, b1, stats);
  k3a_agg2<<<kN / 4, 256, 0, stream>>>((const unsigned*)regA, (const unsigned*)regB,
                                       node_ts, nts, stats, g1, be1, (unsigned*)agg2);
  k3b_gemm2<<<160, 256, 0, stream>>>(agg2, W2, b2, stats, pre2);
  k5_embs<<<kN * 64 / 256, 256, 0, stream>>>(pre2, stats, g2, be2, Wd, embs, embsW);
  k6_loss<<<(2 * kE + 127) / 128, 256, 0, stream>>>(embs, embsW, tgt, neg, bd, out);
}